// Round 18
// baseline (256.622 us; speedup 1.0000x reference)
//
#include <hip/hip_runtime.h>
#include <math.h>

#define BB   2
#define LL   2048
#define HIDD 2048
#define NHH  16
#define HDD  128
#define QKN  4096   // q|k buffer row stride
#define THR2 11.5416f  // defer-max threshold, log2 domain (= 8 nats)
#define EST  136    // v-epilogue LDS row stride (u16): 272B rows, 16B-aligned

typedef unsigned short u16;
typedef float  f32x4 __attribute__((ext_vector_type(4)));
typedef __bf16 bf16x8 __attribute__((ext_vector_type(8)));

static __device__ __forceinline__ float exp2_fast(float x){
  return __builtin_amdgcn_exp2f(x);    // v_exp_f32 (native 2^x)
}
static __device__ __forceinline__ u16 f2bf(float x){
  unsigned u = __float_as_uint(x);
  return (u16)((u + 0x7fffu + ((u >> 16) & 1u)) >> 16);
}
static __device__ __forceinline__ float bf2f(u16 b){
  return __uint_as_float(((unsigned)b) << 16);
}
static __device__ __forceinline__ void gl_lds16(const void* g, void* l){
  __builtin_amdgcn_global_load_lds(
      (__attribute__((address_space(1))) void*)(void*)g,
      (__attribute__((address_space(3))) void*)l,
      16, 0, 0);
}

// ---------------- prep kernels ----------------

__global__ void cvt_f32_bf16_k(const float* __restrict__ src, u16* __restrict__ dst, int n4){
  int i = blockIdx.x * blockDim.x + threadIdx.x;
  if (i >= n4) return;
  float4 v = ((const float4*)src)[i];
  ushort4 o;
  o.x = f2bf(v.x); o.y = f2bf(v.y); o.z = f2bf(v.z); o.w = f2bf(v.w);
  ((ushort4*)dst)[i] = o;
}

// cos/sin table: tab[l*64+d] = (cos(th), sin(th)), th = (l/4)*exp(-d*ln(1e5)/64)
__global__ void rope_table_k(float2* __restrict__ tab){
  int idx = blockIdx.x * blockDim.x + threadIdx.x;   // 2048*64
  int l = idx >> 6, d = idx & 63;
  float fr = __expf(-(float)d * 0.17988946f);
  float th = (float)l * 0.25f * fr;
  float s, c;
  sincosf(th, &s, &c);
  tab[idx] = make_float2(c, s);
}

// fused 4x (2048^2 f32 -> transposed bf16). grid (32,32,4), 256 thr, 64x64 tiles.
__global__ __launch_bounds__(256) void transpose_cvt4_k(
    const float* __restrict__ Wq, const float* __restrict__ Wk,
    const float* __restrict__ Wv, const float* __restrict__ Wo,
    u16* __restrict__ Wt, u16* __restrict__ Wot)
{
  __shared__ u16 t[64][66];
  const int z = blockIdx.z;
  const float* src = (z == 0) ? Wq : (z == 1) ? Wk : (z == 2) ? Wv : Wo;
  u16* dst = (z == 3) ? Wot : (Wt + (size_t)z * 2048 * 2048);
  const int c0 = blockIdx.x * 64, r0 = blockIdx.y * 64;
  const int tid = threadIdx.x;

  #pragma unroll
  for (int i = 0; i < 4; i++){
    int r  = i * 16 + (tid >> 4);
    int c4 = (tid & 15) * 4;
    float4 v = *(const float4*)&src[(size_t)(r0 + r) * 2048 + c0 + c4];
    t[c4 + 0][r] = f2bf(v.x);
    t[c4 + 1][r] = f2bf(v.y);
    t[c4 + 2][r] = f2bf(v.z);
    t[c4 + 3][r] = f2bf(v.w);
  }
  __syncthreads();
  #pragma unroll
  for (int i = 0; i < 2; i++){
    int c  = i * 32 + (tid >> 3);
    int rs = (tid & 7) * 8;
    const unsigned* p = (const unsigned*)&t[c][rs];   // 4B-aligned
    unsigned w0 = p[0], w1 = p[1], w2 = p[2], w3 = p[3];
    u16* d = &dst[(size_t)(c0 + c) * 2048 + r0 + rs];
    ((unsigned*)d)[0] = w0; ((unsigned*)d)[1] = w1;
    ((unsigned*)d)[2] = w2; ((unsigned*)d)[3] = w3;
  }
}

// ---------------- GEMM1: 128x128, fused epilogue, IN-REGISTER rope ----------------
// K-loop = proven 119us structure. B staged with column permutation sigma(r) =
// (r>>6)*32 + ((r>>4)&1)*16 + ((r>>5)&1)*64 + (r&15), so thread-local acc pairs
// (n, n+2) hold rope pairs (d, d+64) -> rope applied in registers, no LDS trip.
// V tiles (sec==2) keep the LDS-transpose epilogue with sigma'd staging column.

__global__ __launch_bounds__(256) void gemm_qkv_k(
    const u16* __restrict__ A, const u16* __restrict__ Bt,
    u16* __restrict__ qk, u16* __restrict__ vt,
    const float2* __restrict__ rtab, int M, int N, int K)
{
  __shared__ __align__(16) u16 SH[17408];      // K-loop: As @0, Bs @8192 (u16 idx)
  u16* As = SH;
  u16* Bs = SH + 8192;
  const int tid = threadIdx.x, lane = tid & 63, wv = tid >> 6;
  const int wr = wv >> 1, wc = wv & 1;
  const int m0 = blockIdx.y * 128, n0 = blockIdx.x * 128;
  const int rq = lane >> 4, cl = lane & 15;

  const f32x4 Z = {0.f, 0.f, 0.f, 0.f};
  f32x4 acc[4][4];
  #pragma unroll
  for (int m = 0; m < 4; m++)
    #pragma unroll
    for (int n = 0; n < 4; n++) acc[m][n] = Z;

  for (int kt = 0; kt < K; kt += 64){
    #pragma unroll
    for (int i = 0; i < 4; i++){
      int fb = (i * 4 + wv) * 64;          // wave-uniform 16B-chunk base
      int p  = (fb + lane) * 16;           // this lane's physical LDS byte
      int r  = p >> 7;                     // tile row (128B rows)
      int cbs = (p & 127) ^ ((r & 7) << 4);
      int sg = ((r >> 6) << 5) + (((r >> 4) & 1) << 4) + (((r >> 5) & 1) << 6) + (r & 15);
      gl_lds16(A  + (size_t)(m0 + r) * K + kt + (cbs >> 1), &As[fb * 8]);
      gl_lds16(Bt + (size_t)(n0 + sg) * K + kt + (cbs >> 1), &Bs[fb * 8]);
    }
    __syncthreads();
    #pragma unroll
    for (int ks = 0; ks < 2; ks++){
      const int kb = ks * 64 + rq * 16;    // k byte offset in row
      bf16x8 a[4], b[4];
      #pragma unroll
      for (int m = 0; m < 4; m++){
        int r = wr * 64 + m * 16 + cl;
        a[m] = *(const bf16x8*)((const char*)As + r * 128 + (kb ^ ((r & 7) << 4)));
      }
      #pragma unroll
      for (int n = 0; n < 4; n++){
        int r = wc * 64 + n * 16 + cl;
        b[n] = *(const bf16x8*)((const char*)Bs + r * 128 + (kb ^ ((r & 7) << 4)));
      }
      #pragma unroll
      for (int m = 0; m < 4; m++)
        #pragma unroll
        for (int n = 0; n < 4; n++)
          acc[m][n] = __builtin_amdgcn_mfma_f32_16x16x32_bf16(a[m], b[n], acc[m][n], 0, 0, 0);
    }
    __syncthreads();
  }

  // ---- fused epilogue ----
  // acc[m][n][rr]: row = wr*64+m*16+rq*4+rr, col = wc*32 + (n&1)*16 + (n>>1)*64 + cl
  const int hd  = n0 >> 7;       // head-column 0..47
  const int sec = hd >> 4;       // 0=q, 1=k, 2=v
  const int hh  = hd & 15;

  if (sec < 2){
    // in-register rope: pairs (acc[m][0],acc[m][2]) at d0, (acc[m][1],acc[m][3]) at d0+16
    const float fsc = (sec == 0) ? 0.12753375f : 1.0f;   // q: 1/sqrt(128)*log2e
    const int d0 = wc * 32 + cl;
    #pragma unroll
    for (int m = 0; m < 4; m++){
      #pragma unroll
      for (int rr = 0; rr < 4; rr++){
        int row = wr * 64 + m * 16 + rq * 4 + rr;
        int l = (m0 + row) & (LL - 1);
        float2 cs0 = rtab[l * 64 + d0];
        float2 cs1 = rtab[l * 64 + d0 + 16];
        float x1a = acc[m][0][rr], x2a = acc[m][2][rr];
        float x1b = acc[m][1][rr], x2b = acc[m][3][rr];
        u16* orow = qk + (size_t)(m0 + row) * QKN + hd * 128;
        orow[d0]      = f2bf((x1a * cs0.x - x2a * cs0.y) * fsc);
        orow[d0 + 64] = f2bf((x1a * cs0.y + x2a * cs0.x) * fsc);
        orow[d0 + 16] = f2bf((x1b * cs1.x - x2b * cs1.y) * fsc);
        orow[d0 + 80] = f2bf((x1b * cs1.y + x2b * cs1.x) * fsc);
      }
    }
  } else {
    // v: stage acc -> LDS (sigma'd column), then transposed 16B writes to vt
    #pragma unroll
    for (int m = 0; m < 4; m++){
      int gr0 = wr * 64 + m * 16 + rq * 4;
      #pragma unroll
      for (int n = 0; n < 4; n++){
        int ec = wc * 32 + (n & 1) * 16 + (n >> 1) * 64 + cl;   // true column
        #pragma unroll
        for (int rr = 0; rr < 4; rr++)
          SH[(gr0 + rr) * EST + ec] = f2bf(acc[m][n][rr]);
      }
    }
    __syncthreads();
    const int d = tid >> 1, l0 = (tid & 1) * 64;
    const int bh = ((m0 >> 11) << 4) + hh;
    u16* vrow = vt + ((size_t)bh * HDD + d) * LL + (m0 & (LL - 1)) + l0;
    #pragma unroll
    for (int g = 0; g < 8; g++){
      bf16x8 o;
      #pragma unroll
      for (int i = 0; i < 8; i++)
        o[i] = *(__bf16*)&SH[(l0 + g * 8 + i) * EST + d];
      *(bf16x8*)(vrow + g * 8) = o;
    }
  }
}

// ---------------- GEMM 128x256 counted-vmcnt (proven for gemm2) ----------------

#define G2_STAGE(kt, bsel) do {                                                           \
  _Pragma("unroll")                                                                       \
  for (int i_ = 0; i_ < 2; i_++){     /* A: 128x64 = 1024 chunks */                       \
    int c_ = ((i_ * 8 + wv) * 64) + lane;                                                 \
    int p_ = c_ * 16;                                                                     \
    int r_ = p_ >> 7; int cb_ = (p_ & 127) ^ ((r_ & 7) << 4);                             \
    gl_lds16(A + (size_t)(m0 + r_) * K + (kt) + (cb_ >> 1),                               \
             &AB[bsel][((i_ * 8 + wv) * 64) * 8]);                                        \
  }                                                                                       \
  _Pragma("unroll")                                                                       \
  for (int i_ = 0; i_ < 4; i_++){     /* B: 256x64 = 2048 chunks */                       \
    int c_ = ((i_ * 8 + wv) * 64) + lane;                                                 \
    int p_ = c_ * 16;                                                                     \
    int r_ = p_ >> 7; int cb_ = (p_ & 127) ^ ((r_ & 7) << 4);                             \
    gl_lds16(Bt + (size_t)(n0 + r_) * K + (kt) + (cb_ >> 1),                              \
             &AB[bsel][8192 + ((i_ * 8 + wv) * 64) * 8]);                                 \
  }                                                                                       \
} while(0)

template<int OUT_BF16>
__global__ __launch_bounds__(512, 1) void gemm_bt2_k(
    const u16* __restrict__ A, const u16* __restrict__ Bt,
    void* __restrict__ Cout, int M, int N, int K)
{
  __shared__ __align__(16) u16 AB[2][24576];   // per buf: A[128][64] @0, B[256][64] @8192
  const int tid = threadIdx.x, lane = tid & 63, wv = tid >> 6;
  const int wr = wv >> 2, wc = wv & 3;          // 2 (M) x 4 (N) waves
  const int m0 = blockIdx.y * 128, n0 = blockIdx.x * 256;
  const int rq = lane >> 4, cl = lane & 15;
  const int NT = K >> 6;                        // 64-wide K tiles

  const f32x4 Z = {0.f, 0.f, 0.f, 0.f};
  f32x4 acc[4][4];
  #pragma unroll
  for (int m = 0; m < 4; m++)
    #pragma unroll
    for (int n = 0; n < 4; n++) acc[m][n] = Z;

  G2_STAGE(0, 0);
  G2_STAGE(64, 1);
  asm volatile("s_waitcnt vmcnt(6)");
  __builtin_amdgcn_sched_barrier(0);
  __builtin_amdgcn_s_barrier();

  int cur = 0;
  for (int t = 0; t < NT; t++){
    const char* As_ = (const char*)&AB[cur][0];
    const char* Bs_ = (const char*)&AB[cur][8192];

    #pragma unroll
    for (int ks = 0; ks < 2; ks++){
      const int kb = ks * 64 + rq * 16;
      bf16x8 a[4], b[4];
      #pragma unroll
      for (int m = 0; m < 4; m++){
        int r = wr * 64 + m * 16 + cl;
        a[m] = *(const bf16x8*)(As_ + r * 128 + (kb ^ ((r & 7) << 4)));
      }
      #pragma unroll
      for (int n = 0; n < 4; n++){
        int r = wc * 64 + n * 16 + cl;
        b[n] = *(const bf16x8*)(Bs_ + r * 128 + (kb ^ ((r & 7) << 4)));
      }
      __builtin_amdgcn_s_setprio(1);
      #pragma unroll
      for (int m = 0; m < 4; m++)
        #pragma unroll
        for (int n = 0; n < 4; n++)
          acc[m][n] = __builtin_amdgcn_mfma_f32_16x16x32_bf16(a[m], b[n], acc[m][n], 0, 0, 0);
      __builtin_amdgcn_s_setprio(0);
    }

    __builtin_amdgcn_sched_barrier(0);
    __builtin_amdgcn_s_barrier();              // every wave done READING buf[cur]

    if (t + 2 < NT){
      G2_STAGE((t + 2) * 64, cur);             // overwrite freed buffer
      asm volatile("s_waitcnt vmcnt(6)");      // tile t+1 landed; t+2 stays in flight
    } else {
      asm volatile("s_waitcnt vmcnt(0)");      // tail: drain remaining
    }
    __builtin_amdgcn_sched_barrier(0);
    __builtin_amdgcn_s_barrier();              // every wave's tile t+1 landed
    cur ^= 1;
  }

  #pragma unroll
  for (int m = 0; m < 4; m++){
    int gr0 = m0 + wr * 64 + m * 16 + rq * 4;
    #pragma unroll
    for (int n = 0; n < 4; n++){
      int gc = n0 + wc * 64 + n * 16 + cl;
      #pragma unroll
      for (int rr = 0; rr < 4; rr++){
        if (OUT_BF16) ((u16*)Cout)[(size_t)(gr0 + rr) * N + gc] = f2bf(acc[m][n][rr]);
        else          ((float*)Cout)[(size_t)(gr0 + rr) * N + gc] = acc[m][n][rr];
      }
    }
  }
}

// ---------------- flash attention v6 (proven): deep K+V prefetch ----------

#define STAGE_K(jj, bsel) do {                                                            \
  _Pragma("unroll")                                                                       \
  for (int i_ = 0; i_ < 4; i_++){                                                         \
    int fb_ = (i_ * 4 + wv) * 64;                                                         \
    int p_  = (fb_ + lane) * 16;                                                          \
    int r_ = p_ >> 8; int cb_ = (p_ & 255) ^ ((r_ & 7) << 4);                             \
    gl_lds16(qk + (size_t)(b * LL + (jj) * 64 + r_) * QKN + 2048 + h * HDD + (cb_ >> 1),  \
             &Kb[bsel][fb_ * 8]);                                                         \
  }                                                                                       \
} while(0)

#define STAGE_V(jj, bsel) do {                                                            \
  _Pragma("unroll")                                                                       \
  for (int i_ = 0; i_ < 4; i_++){                                                         \
    int fb_ = (i_ * 4 + wv) * 64;                                                         \
    int p_  = (fb_ + lane) * 16;                                                          \
    int r_ = p_ >> 7; int cb_ = (p_ & 127) ^ ((r_ & 7) << 4);                             \
    gl_lds16(vt + (size_t)(bh * HDD + r_) * LL + (jj) * 64 + (cb_ >> 1),                  \
             &Vb[bsel][fb_ * 8]);                                                         \
  }                                                                                       \
} while(0)

__global__ __launch_bounds__(256, 2) void attn_k(
    const u16* __restrict__ qk, const u16* __restrict__ vt,
    u16* __restrict__ aout)
{
  __shared__ __align__(16) u16 Kb[2][64 * 128];   // K tiles, 2x16KB
  __shared__ __align__(16) u16 Vb[2][128 * 64];   // V^T tiles, 2x16KB
  __shared__ __align__(16) u16 Ps[4][1024];       // per-wave P tile 16x64, 8KB
  const int tid = threadIdx.x, lane = tid & 63, wv = tid >> 6;
  const int bh = blockIdx.x;                      // fast dim -> XCD = bh % 8
  const int pr = blockIdx.y;                      // pair index 0..15
  const int b = bh >> 4, h = bh & 15;
  const int rq = lane >> 4, cl = lane & 15;

  bf16x8 ones;
  #pragma unroll
  for (int i = 0; i < 8; i++) ones[i] = (__bf16)1.0f;
  const f32x4 Z = {0.f, 0.f, 0.f, 0.f};

  int cur = 0;
  STAGE_V(0, 0);                                  // phase-A tile 0 (V older in queue)
  STAGE_K(0, 0);

  #pragma unroll
  for (int ph = 0; ph < 2; ph++){
    const int qt = ph ? pr : (31 - pr);           // 64-row q-tile index
    const int nj = qt + 1;

    bf16x8 qf[4];
    {
      const u16* qb = qk + (size_t)(b * LL + qt * 64 + wv * 16 + cl) * QKN + h * HDD + rq * 8;
      #pragma unroll
      for (int ks = 0; ks < 4; ks++) qf[ks] = *(const bf16x8*)(qb + ks * 32);
    }

    f32x4 acco[8], accl;
    float mst[4];
    #pragma unroll
    for (int n = 0; n < 8; n++) acco[n] = Z;
    accl = Z;
    #pragma unroll
    for (int rr = 0; rr < 4; rr++) mst[rr] = -INFINITY;

    for (int j = 0; j < nj; j++){
      const bool sn = (j + 1 < nj) || (ph == 0);  // stages a next tile this iter
      if (j + 1 < nj){      STAGE_V(j + 1, cur ^ 1); STAGE_K(j + 1, cur ^ 1); }
      else if (ph == 0){    STAGE_V(0,     cur ^ 1); STAGE_K(0,     cur ^ 1); }
      __builtin_amdgcn_sched_barrier(0);
      if (sn) asm volatile("s_waitcnt vmcnt(8)" ::: "memory");  // tile j fully landed
      else    asm volatile("s_waitcnt vmcnt(0)" ::: "memory");
      __builtin_amdgcn_sched_barrier(0);
      __builtin_amdgcn_s_barrier();               // all waves' K(j),V(j) landed
      __builtin_amdgcn_sched_barrier(0);

      // S = Q K^T (16 q-rows x 64 kv per wave)
      f32x4 sv[4];
      {
        const char* KsC = (const char*)&Kb[cur][0];
        #pragma unroll
        for (int ct = 0; ct < 4; ct++) sv[ct] = Z;
        #pragma unroll
        for (int ks = 0; ks < 4; ks++){
          const int kb = ks * 64 + rq * 16;
          #pragma unroll
          for (int ct = 0; ct < 4; ct++){
            int r = ct * 16 + cl;
            bf16x8 bfr = *(const bf16x8*)(KsC + r * 256 + (kb ^ ((r & 7) << 4)));
            sv[ct] = __builtin_amdgcn_mfma_f32_16x16x32_bf16(qf[ks], bfr, sv[ct], 0, 0, 0);
          }
        }
      }

      // softmax (exp2 domain) + P write into own Ps slot (in-wave RAW ordering)
      {
        char* pbase = (char*)&Ps[wv][0];
        const bool msk = (j == qt);                 // diagonal tile only

        float p4[4][4], lmx[4];
        #pragma unroll
        for (int rr = 0; rr < 4; rr++) lmx[rr] = -1e30f;
        const int qg = qt * 64 + wv * 16 + rq * 4;
        #pragma unroll
        for (int ct = 0; ct < 4; ct++){
          int col = j * 64 + ct * 16 + cl;
          #pragma unroll
          for (int rr = 0; rr < 4; rr++){
            float v = sv[ct][rr];                   // already log2-domain
            if (msk && col > qg + rr) v = -1e30f;
            p4[ct][rr] = v;
            lmx[rr] = fmaxf(lmx[rr], v);
          }
        }
        float need = -1e30f;
        #pragma unroll
        for (int rr = 0; rr < 4; rr++) need = fmaxf(need, lmx[rr] - mst[rr]);
        if (__any(need > THR2)){
          float mx[4];
          #pragma unroll
          for (int rr = 0; rr < 4; rr++) mx[rr] = lmx[rr];
          #pragma unroll
          for (int off = 1; off < 16; off <<= 1)
            #pragma unroll
            for (int rr = 0; rr < 4; rr++)
              mx[rr] = fmaxf(mx[rr], __shfl_xor(mx[rr], off, 64));
          #pragma unroll
          for (int rr = 0; rr < 4; rr++){
            float mn  = fmaxf(mst[rr], mx[rr]);
            float fsc = exp2_fast(mst[rr] - mn);
            mst[rr] = mn;
            accl[rr] *= fsc;
            #pragma unroll
            for (int n = 0; n < 8; n++) acco[n][rr] *= fsc;
          }
        }
        #pragma unroll
        for (int ct = 0; ct < 4; ct++)
          #pragma unroll
          for (int rr = 0; rr < 4; rr++){
            float e = exp2_fast(p4[ct][rr] - mst[rr]);
            int wr = rq * 4 + rr;
            *(u16*)(pbase + wr * 128 + (((ct * 16 + cl) * 2) ^ ((wr & 7) << 4))) = f2bf(e);
          }
      }

      // O += P V ; l += P 1  (V already resident; no mid-iter wait)
      {
        const char* VsC = (const char*)&Vb[cur][0];
        char* pbase = (char*)&Ps[wv][0];
        #pragma unroll
        for (int ks = 0; ks < 2; ks++){
          const int kvb = ks * 64 + rq * 16;
          bf16x8 pa = *(const bf16x8*)(pbase + cl * 128 + (kvb ^ ((cl & 7) << 4)));
          accl = __builtin_amdgcn_mfma_f32_16x16x32_bf16(pa, ones, accl, 0, 0, 0);
          #pragma unroll
          for (int n = 0; n < 8; n++){
            int r = n * 16 + cl;
            bf16x8 bfr = *(const bf16x8*)(VsC + r * 128 + (kvb ^ ((r & 7) << 4)));
            acco[n] = __builtin_amdgcn_mfma_f32_16x16x32_bf16(pa, bfr, acco[n], 0, 0, 0);
          }
        }
      }

      __builtin_amdgcn_sched_barrier(0);
      __builtin_amdgcn_s_barrier();               // reads of buf[cur] done before overwrite
      __builtin_amdgcn_sched_barrier(0);
      cur ^= 1;
    }

    // direct write-out
    #pragma unroll
    for (int rr = 0; rr < 4; rr++){
      float inv = 1.0f / accl[rr];
      size_t grow = (size_t)(b * LL + qt * 64 + wv * 16 + rq * 4 + rr);
      #pragma unroll
      for (int n = 0; n < 8; n++)
        aout[grow * HIDD + h * HDD + n * 16 + cl] = f2bf(acco[n][rr] * inv);
    }
  }
}

// ---------------- launcher ----------------

extern "C" void kernel_launch(void* const* d_in, const int* in_sizes, int n_in,
                              void* d_out, int out_size, void* d_ws, size_t ws_size,
                              hipStream_t stream)
{
  const float* x  = (const float*)d_in[0];
  // d_in[1] = mask (causal; applied analytically)
  const float* Wq = (const float*)d_in[2];
  const float* Wk = (const float*)d_in[3];
  const float* Wv = (const float*)d_in[4];
  const float* Wo = (const float*)d_in[5];
  float* out = (float*)d_out;

  if (ws_size < 120586240ull) return;  // need ~115 MB of scratch

  char* ws = (char*)d_ws;
  u16*    xb   = (u16*)(ws);                   // 4096x2048 bf16   (16 MB)
  u16*    Wt   = (u16*)(ws + 16777216ull);     // 6144x2048 bf16   (24 MB) = [Wq|Wk|Wv]^T
  u16*    Wot  = (u16*)(ws + 41943040ull);     // 2048x2048 bf16   ( 8 MB)
  u16*    qk   = (u16*)(ws + 50331648ull);     // 4096x4096 bf16   (32 MB) roped q|k
  u16*    vt   = (u16*)(ws + 83886080ull);     // 32x128x2048 bf16 (16 MB)
  u16*    aout = (u16*)(ws + 100663296ull);    // 4096x2048 bf16   (16 MB)
  float2* rtab = (float2*)(ws + 117440512ull); // 2048x64 float2   ( 1 MB)

  cvt_f32_bf16_k<<<2097152 / 256, 256, 0, stream>>>(x, xb, 2097152);
  rope_table_k<<<131072 / 256, 256, 0, stream>>>(rtab);
  transpose_cvt4_k<<<dim3(32, 32, 4), 256, 0, stream>>>(Wq, Wk, Wv, Wo, Wt, Wot);

  gemm_qkv_k<<<dim3(6144 / 128, 4096 / 128), 256, 0, stream>>>(xb, Wt, qk, vt, rtab, 4096, 6144, 2048);

  attn_k<<<dim3(32, 16), 256, 0, stream>>>(qk, vt, aout);

  gemm_bt2_k<0><<<dim3(2048 / 256, 4096 / 128), 512, 0, stream>>>(aout, Wot, out, 4096, 2048, 2048);
}